// Round 1
// baseline (122.695 us; speedup 1.0000x reference)
//
#include <hip/hip_runtime.h>
#include <hip/hip_bf16.h>

// Problem constants
#define B_   32
#define N_   2048
#define E_   768
#define OUT_ 384
#define HID_ 16
constexpr int ROWS   = B_ * N_;      // 65536
constexpr int TILE_M = 16;           // rows per block
constexpr int NT     = OUT_ / 16;    // 24 N-tiles of local GEMM
constexpr int KT_L   = 192 / 32;     // 6 K-steps (local, K=192)
constexpr int KT_G   = E_ / 32;      // 24 K-steps (gate, K=768)
constexpr int XS_STRIDE = 772;       // padded LDS row stride in floats (3088B, 16B aligned)

typedef __attribute__((ext_vector_type(8))) short bf16x8;
typedef __attribute__((ext_vector_type(4))) float f32x4;

__device__ __forceinline__ short f2bf(float f) {
  union { float f; unsigned u; } v; v.f = f;
  unsigned r = v.u + 0x7fffu + ((v.u >> 16) & 1u);   // RNE
  return (short)(r >> 16);
}

// ---------------- pre-pass: build bf16 MFMA B-fragments in workspace ----------------
// wsL: [NT][KT_L][64 lanes][8]  (w_l fragments)   wsG: [KT_G][64][8] (w_g1 fragments)
__global__ void prep_kernel(const float* __restrict__ w_l, const float* __restrict__ w_g1,
                            short* __restrict__ wsL, short* __restrict__ wsG) {
  int t = blockIdx.x * blockDim.x + threadIdx.x;
  int wave = t >> 6, ln = t & 63;
  int kg = ln >> 4, c16 = ln & 15;
  if (wave < NT * KT_L) {
    int n = wave / KT_L, ks = wave % KT_L;
    bf16x8 v;
#pragma unroll
    for (int j = 0; j < 8; ++j) {
      int k = ks * 32 + kg * 8 + j;               // local K index
      v[j] = f2bf(w_l[k * OUT_ + n * 16 + c16]);
    }
    *reinterpret_cast<bf16x8*>(&wsL[(size_t)(wave * 64 + ln) * 8]) = v;
  } else if (wave < NT * KT_L + KT_G) {
    int ks = wave - NT * KT_L;
    bf16x8 v;
#pragma unroll
    for (int j = 0; j < 8; ++j) {
      int k = ks * 32 + kg * 8 + j;               // gate K index
      v[j] = f2bf(w_g1[k * HID_ + c16]);
    }
    *reinterpret_cast<bf16x8*>(&wsG[(size_t)(ks * 64 + ln) * 8]) = v;
  }
}

// ---------------- main fused kernel ----------------
template <bool USE_WS>
__global__ __launch_bounds__(256)
void spectre_kernel(const float* __restrict__ x,
                    const float* __restrict__ w_g1, const float* __restrict__ b_g1,
                    const float* __restrict__ ln_g_w, const float* __restrict__ ln_g_b,
                    const float* __restrict__ w_g2, const float* __restrict__ b_g2,
                    const float* __restrict__ w_l, const float* __restrict__ b_l,
                    const float* __restrict__ ln_l_w, const float* __restrict__ ln_l_b,
                    const short* __restrict__ wsL, const short* __restrict__ wsG,
                    float* __restrict__ out) {
  __shared__ float xs[TILE_M * XS_STRIDE];   // 49408 B, x tile in f32
  __shared__ float red2[4][16][16];          // gate partial sums per wave
  __shared__ float reds[4][16][2];           // local LN partial (s1,s2) per wave

  const int tid = threadIdx.x;
  const int wv  = tid >> 6;        // wave 0..3
  const int ln  = tid & 63;        // lane
  const int kg  = ln >> 4;         // k-group / D-row group
  const int l15 = ln & 15;         // A-row / D-col
  const int row0 = blockIdx.x * TILE_M;

  // ---- stage 16 rows x 768 f32 into LDS (async, coalesced, 16B/lane) ----
  {
    const float* g = x + (size_t)(row0 + wv * 4) * E_ + ln * 4;
#pragma unroll
    for (int r = 0; r < 4; ++r) {
#pragma unroll
      for (int c = 0; c < 3; ++c) {
        __builtin_amdgcn_global_load_lds(
            (const __attribute__((address_space(1))) void*)(g + r * E_ + c * 256),
            (__attribute__((address_space(3))) void*)(&xs[(wv * 4 + r) * XS_STRIDE + c * 256]),
            16, 0, 0);
      }
    }
  }
  asm volatile("s_waitcnt vmcnt(0)" ::: "memory");
  __syncthreads();

  // ---- gate GEMM partial: wave wv handles K-steps [6wv, 6wv+6) ----
  f32x4 accg = {0.f, 0.f, 0.f, 0.f};
#pragma unroll
  for (int i = 0; i < 6; ++i) {
    const int ks = wv * 6 + i;
    const float* p = &xs[l15 * XS_STRIDE + ks * 32 + kg * 8];
    const float4 u0 = *(const float4*)(p);
    const float4 u1 = *(const float4*)(p + 4);
    bf16x8 a = { f2bf(u0.x), f2bf(u0.y), f2bf(u0.z), f2bf(u0.w),
                 f2bf(u1.x), f2bf(u1.y), f2bf(u1.z), f2bf(u1.w) };
    bf16x8 b;
    if constexpr (USE_WS) {
      b = *reinterpret_cast<const bf16x8*>(&wsG[(size_t)(ks * 64 + ln) * 8]);
    } else {
#pragma unroll
      for (int j = 0; j < 8; ++j) b[j] = f2bf(w_g1[(ks * 32 + kg * 8 + j) * HID_ + l15]);
    }
    accg = __builtin_amdgcn_mfma_f32_16x16x32_bf16(a, b, accg, 0, 0, 0);
  }
#pragma unroll
  for (int r = 0; r < 4; ++r) red2[wv][kg * 4 + r][l15] = accg[r];

  // ---- local GEMM: A-frags (every 4th x element) loaded once, reused over 6 N-tiles ----
  bf16x8 aL[6];
#pragma unroll
  for (int ks = 0; ks < 6; ++ks) {
    const float* p = &xs[l15 * XS_STRIDE + ks * 128 + kg * 32];  // x col = 4*k
    bf16x8 a;
#pragma unroll
    for (int j = 0; j < 8; ++j) a[j] = f2bf(p[4 * j]);
    aL[ks] = a;
  }

  f32x4 acc[6];
#pragma unroll
  for (int n = 0; n < 6; ++n) acc[n] = (f32x4){0.f, 0.f, 0.f, 0.f};
#pragma unroll
  for (int n = 0; n < 6; ++n) {
    const int ng = wv * 6 + n;
#pragma unroll
    for (int ks = 0; ks < 6; ++ks) {
      bf16x8 b;
      if constexpr (USE_WS) {
        b = *reinterpret_cast<const bf16x8*>(&wsL[(size_t)((ng * KT_L + ks) * 64 + ln) * 8]);
      } else {
#pragma unroll
        for (int j = 0; j < 8; ++j)
          b[j] = f2bf(w_l[(ks * 32 + kg * 8 + j) * OUT_ + ng * 16 + l15]);
      }
      acc[n] = __builtin_amdgcn_mfma_f32_16x16x32_bf16(aL[ks], b, acc[n], 0, 0, 0);
    }
  }

  // ---- add b_l, per-row LN stats (this wave's 96 cols) ----
  float lw[6], lb[6];
  float s1[4] = {0.f, 0.f, 0.f, 0.f}, s2[4] = {0.f, 0.f, 0.f, 0.f};
#pragma unroll
  for (int n = 0; n < 6; ++n) {
    const int col = (wv * 6 + n) * 16 + l15;
    const float bln = b_l[col];
    lw[n] = ln_l_w[col];
    lb[n] = ln_l_b[col];
#pragma unroll
    for (int r = 0; r < 4; ++r) {
      const float v = acc[n][r] + bln;
      acc[n][r] = v;
      s1[r] += v;
      s2[r] += v * v;
    }
  }
#pragma unroll
  for (int m = 1; m < 16; m <<= 1) {
#pragma unroll
    for (int r = 0; r < 4; ++r) {
      s1[r] += __shfl_xor(s1[r], m);
      s2[r] += __shfl_xor(s2[r], m);
    }
  }
  if (l15 == 0) {
#pragma unroll
    for (int r = 0; r < 4; ++r) {
      reds[wv][kg * 4 + r][0] = s1[r];
      reds[wv][kg * 4 + r][1] = s2[r];
    }
  }
  __syncthreads();

  // ---- gate finalize: combine wave partials, LN over 16, GeLU, dot w_g2 ----
  const float bg  = b_g1[l15];
  const float lgw = ln_g_w[l15];
  const float lgb = ln_g_b[l15];
  const float wg2 = w_g2[l15];
  const float bg2 = b_g2[0];
  float gf[4];
#pragma unroll
  for (int r = 0; r < 4; ++r) {
    const int row = kg * 4 + r;
    float y = red2[0][row][l15] + red2[1][row][l15] + red2[2][row][l15] + red2[3][row][l15] + bg;
    float s = y;
#pragma unroll
    for (int m = 1; m < 16; m <<= 1) s += __shfl_xor(s, m);
    const float mean = s * (1.f / 16.f);
    const float d = y - mean;
    float q = d * d;
#pragma unroll
    for (int m = 1; m < 16; m <<= 1) q += __shfl_xor(q, m);
    const float rstd = rsqrtf(q * (1.f / 16.f) + 1e-5f);
    const float vn = d * rstd * lgw + lgb;
    const float gl = 0.5f * vn * (1.f + erff(vn * 0.70710678118654752f));
    float ps = gl * wg2;
#pragma unroll
    for (int m = 1; m < 16; m <<= 1) ps += __shfl_xor(ps, m);
    gf[r] = ps + bg2;
  }

  // ---- local finalize: LN over 384 via cross-wave sums, GeLU, + pooled + gate ----
  float meanr[4], rstdr[4];
#pragma unroll
  for (int r = 0; r < 4; ++r) {
    const int row = kg * 4 + r;
    const float t1 = reds[0][row][0] + reds[1][row][0] + reds[2][row][0] + reds[3][row][0];
    const float t2 = reds[0][row][1] + reds[1][row][1] + reds[2][row][1] + reds[3][row][1];
    meanr[r] = t1 * (1.f / 384.f);
    const float var = t2 * (1.f / 384.f) - meanr[r] * meanr[r];
    rstdr[r] = rsqrtf(var + 1e-5f);
  }
#pragma unroll
  for (int n = 0; n < 6; ++n) {
    const int col = (wv * 6 + n) * 16 + l15;
#pragma unroll
    for (int r = 0; r < 4; ++r) {
      const int row = kg * 4 + r;
      const float2 px = *(const float2*)&xs[row * XS_STRIDE + 2 * col];
      const float pooled = 0.5f * (px.x + px.y);
      const float vn = (acc[n][r] - meanr[r]) * rstdr[r] * lw[n] + lb[n];
      const float gl = 0.5f * vn * (1.f + erff(vn * 0.70710678118654752f));
      out[(size_t)(row0 + row) * OUT_ + col] = gl + gf[r] + pooled;
    }
  }
}

// ---------------- launch ----------------
extern "C" void kernel_launch(void* const* d_in, const int* in_sizes, int n_in,
                              void* d_out, int out_size, void* d_ws, size_t ws_size,
                              hipStream_t stream) {
  (void)in_sizes; (void)n_in; (void)out_size;
  const float* x      = (const float*)d_in[0];
  const float* w_g1   = (const float*)d_in[1];
  const float* b_g1   = (const float*)d_in[2];
  const float* ln_g_w = (const float*)d_in[3];
  const float* ln_g_b = (const float*)d_in[4];
  const float* w_g2   = (const float*)d_in[5];
  const float* b_g2   = (const float*)d_in[6];
  const float* w_l    = (const float*)d_in[7];
  const float* b_l    = (const float*)d_in[8];
  const float* ln_l_w = (const float*)d_in[9];
  const float* ln_l_b = (const float*)d_in[10];
  float* out = (float*)d_out;

  const size_t needL = (size_t)NT * KT_L * 64 * 8;   // shorts
  const size_t needG = (size_t)KT_G * 64 * 8;        // shorts
  const bool use_ws = ws_size >= (needL + needG) * sizeof(short);

  short* wsL = (short*)d_ws;
  short* wsG = wsL + needL;

  const int grid = ROWS / TILE_M;   // 4096
  if (use_ws) {
    prep_kernel<<<(NT * KT_L + KT_G) * 64 / 256, 256, 0, stream>>>(w_l, w_g1, wsL, wsG);
    spectre_kernel<true><<<grid, 256, 0, stream>>>(x, w_g1, b_g1, ln_g_w, ln_g_b, w_g2, b_g2,
                                                   w_l, b_l, ln_l_w, ln_l_b, wsL, wsG, out);
  } else {
    spectre_kernel<false><<<grid, 256, 0, stream>>>(x, w_g1, b_g1, ln_g_w, ln_g_b, w_g2, b_g2,
                                                    w_l, b_l, ln_l_w, ln_l_b, nullptr, nullptr, out);
  }
}